// Round 15
// baseline (780.311 us; speedup 1.0000x reference)
//
#include <hip/hip_runtime.h>
#include <hip/hip_bf16.h>
#include <hip/hip_fp16.h>

#define N_NODES 100000
#define N_EDGES 1600000
#define D 32
#define N_GRAPHS 128

#define WIN 128                                   // nodes per window
#define NWINS ((N_NODES + WIN - 1) / WIN)         // 782
#define CAP 2560                                  // bucket capacity (mean 2046)
#define NODES_PER_WAVE 8
#define L2_BLOCKS 512
#define RED_BLOCKS 64

// ---- Stage 1: bin edges by 128-node DST window, coalesced bucket writes ----
__global__ void bin_kernel(const int* __restrict__ src,
                           const int* __restrict__ dst,
                           int* __restrict__ gfill,
                           int* __restrict__ ebuf) {
    __shared__ int lhist[NWINS];
    __shared__ int lbase[NWINS];
    const int tid = threadIdx.x;
    const int per = (N_EDGES + gridDim.x - 1) / gridDim.x;
    const int e0 = blockIdx.x * per;
    const int e1 = (e0 + per < N_EDGES) ? e0 + per : N_EDGES;

    for (int b = tid; b < NWINS; b += blockDim.x) lhist[b] = 0;
    __syncthreads();
    for (int e = e0 + tid; e < e1; e += blockDim.x)
        atomicAdd(&lhist[dst[e] >> 7], 1);
    __syncthreads();
    for (int b = tid; b < NWINS; b += blockDim.x) {
        int c = lhist[b];
        lbase[b] = c ? atomicAdd(&gfill[b], c) : 0;
        lhist[b] = 0;
    }
    __syncthreads();
    for (int e = e0 + tid; e < e1; e += blockDim.x) {
        int d = dst[e];
        int bn = d >> 7;
        int r = atomicAdd(&lhist[bn], 1);
        int off = lbase[bn] + r;
        if (off < CAP) ebuf[bn * CAP + off] = ((d & (WIN - 1)) << 17) | src[e];
    }
}

// ---- Stage 2: exclusive scan of window counts ----
__global__ void wscan_kernel(const int* __restrict__ gfill, int* __restrict__ wbase) {
    __shared__ int s[1024];
    const int t = threadIdx.x;
    int v = (t < NWINS) ? gfill[t] : 0;
    s[t] = v;
    __syncthreads();
    for (int off = 1; off < 1024; off <<= 1) {
        int a = (t >= off) ? s[t - off] : 0;
        __syncthreads();
        s[t] += a;
        __syncthreads();
    }
    if (t < NWINS) wbase[t] = s[t] - v;
    if (t == NWINS - 1) wbase[NWINS] = s[t];
}

// ---- Stage 3: per-window LDS sort -> dst-sorted CSR; edge words carry the
// dst's graph id packed in the high bits: word = (gdst<<17) | src ----
__global__ void csr_local_kernel(const int* __restrict__ ebuf,
                                 const int* __restrict__ wbase,
                                 const int* __restrict__ graph_ids,
                                 int* __restrict__ esrc,
                                 int* __restrict__ rend,
                                 int* __restrict__ deg) {
    __shared__ int pk[CAP];
    __shared__ int ssrc[CAP];
    __shared__ int hs[WIN];
    __shared__ int hcnt[WIN];
    __shared__ int cur[WIN];
    __shared__ int gwv[WIN];
    const int tid = threadIdx.x;
    const int w = blockIdx.x;
    const int base_out = wbase[w];
    int cnt = wbase[w + 1] - base_out;
    if (cnt > CAP) cnt = CAP;
    const int n0 = w * WIN;

    for (int i = tid; i < cnt; i += 256) pk[i] = ebuf[w * CAP + i];
    if (tid < WIN) {
        hcnt[tid] = 0;
        const int n = n0 + tid;
        gwv[tid] = (n < N_NODES) ? graph_ids[n] : 0;
    }
    __syncthreads();
    for (int i = tid; i < cnt; i += 256) atomicAdd(&hcnt[pk[i] >> 17], 1);
    __syncthreads();
    if (tid < WIN) hs[tid] = hcnt[tid];
    __syncthreads();
    for (int off = 1; off < WIN; off <<= 1) {
        int a = 0;
        if (tid < WIN && tid >= off) a = hs[tid - off];
        __syncthreads();
        if (tid < WIN) hs[tid] += a;
        __syncthreads();
    }
    if (tid < WIN) {
        const int incl = hs[tid];
        const int c = hcnt[tid];
        cur[tid] = incl - c;
        const int n = n0 + tid;
        if (n < N_NODES) { rend[n] = base_out + incl; deg[n] = c; }
    }
    __syncthreads();
    for (int i = tid; i < cnt; i += 256) {
        const int p = pk[i];
        const int dloc = p >> 17;
        const int pos = atomicAdd(&cur[dloc], 1);
        ssrc[pos] = (gwv[dloc] << 17) | (p & 0x1FFFF);
    }
    __syncthreads();
    for (int i = tid; i < cnt; i += 256) esrc[base_out + i] = ssrc[i];
}

// ---- Stage 4: re-bin packed edges by SRC window; payload (gdst<<7|srcloc) ----
__global__ void bin2_kernel(const int* __restrict__ epk,
                            int* __restrict__ gfill2,
                            int* __restrict__ ebuf2) {
    __shared__ int lhist[NWINS];
    __shared__ int lbase[NWINS];
    const int tid = threadIdx.x;
    const int per = (N_EDGES + gridDim.x - 1) / gridDim.x;
    const int e0 = blockIdx.x * per;
    const int e1 = (e0 + per < N_EDGES) ? e0 + per : N_EDGES;

    for (int b = tid; b < NWINS; b += blockDim.x) lhist[b] = 0;
    __syncthreads();
    for (int e = e0 + tid; e < e1; e += blockDim.x)
        atomicAdd(&lhist[(epk[e] & 0x1FFFF) >> 7], 1);
    __syncthreads();
    for (int b = tid; b < NWINS; b += blockDim.x) {
        int c = lhist[b];
        lbase[b] = c ? atomicAdd(&gfill2[b], c) : 0;
        lhist[b] = 0;
    }
    __syncthreads();
    for (int e = e0 + tid; e < e1; e += blockDim.x) {
        const int wd = epk[e];
        const int s = wd & 0x1FFFF;
        const int bn = s >> 7;
        int r = atomicAdd(&lhist[bn], 1);
        int off = lbase[bn] + r;
        if (off < CAP) ebuf2[bn * CAP + off] = ((wd >> 17) << 7) | (s & (WIN - 1));
    }
}

// ---- f16 helpers ----
__device__ __forceinline__ unsigned pkh2(float a, float b) {
    __half2 h = __floats2half2_rn(a, b);
    return *reinterpret_cast<unsigned*>(&h);
}
__device__ __forceinline__ unsigned hadd2u(unsigned a, unsigned b) {
    __half2 ha = *reinterpret_cast<__half2*>(&a);
    __half2 hb = *reinterpret_cast<__half2*>(&b);
    __half2 r = __hadd2(ha, hb);
    return *reinterpret_cast<unsigned*>(&r);
}
__device__ __forceinline__ float lo2f(unsigned u) { return __low2float(*reinterpret_cast<__half2*>(&u)); }
__device__ __forceinline__ float hi2f(unsigned u) { return __high2float(*reinterpret_cast<__half2*>(&u)); }

__global__ void f32_to_f16_kernel(const float* __restrict__ in, uint4* __restrict__ out) {
    const int i = blockIdx.x * blockDim.x + threadIdx.x;
    if (i >= N_NODES * D / 8) return;
    const float4* p = reinterpret_cast<const float4*>(in) + (size_t)i * 2;
    const float4 v0 = p[0], v1 = p[1];
    uint4 o;
    o.x = pkh2(v0.x, v0.y); o.y = pkh2(v0.z, v0.w);
    o.z = pkh2(v1.x, v1.y); o.w = pkh2(v1.z, v1.w);
    out[i] = o;
}

// per-graph node counts (for the b2 term)
__global__ void cnt_hist_kernel(const int* __restrict__ graph_ids, int* __restrict__ cnt) {
    const int i = blockIdx.x * blockDim.x + threadIdx.x;
    if (i < N_NODES) atomicAdd(&cnt[graph_ids[i]], 1);
}

#define PK_ADD(g) do { \
    acc01 = hadd2u(acc01, (g).x); acc23 = hadd2u(acc23, (g).y); \
    acc45 = hadd2u(acc45, (g).z); acc67 = hadd2u(acc67, (g).w); } while (0)

// ---- Layer 1 (pull-gather, proven round-12 structure; esrc words masked) ----
__global__ void gin_layer1_kernel(const uint4* __restrict__ xh,
                                  const int* __restrict__ esrc,
                                  const int* __restrict__ rend,
                                  const int* __restrict__ deg,
                                  const float* __restrict__ W,
                                  const float* __restrict__ bias,
                                  uint2* __restrict__ outh) {
    const int lane = threadIdx.x & 63;
    const int fq = lane & 3;
    const int es = lane >> 2;
    const int og = lane & 7;
    const int ig = lane >> 3;

    float w[4][4];
#pragma unroll
    for (int k = 0; k < 4; ++k) {
        const float4 t = *reinterpret_cast<const float4*>(&W[(ig * 4 + k) * D + og * 4]);
        w[k][0] = t.x; w[k][1] = t.y; w[k][2] = t.z; w[k][3] = t.w;
    }
    const float4 bv = *reinterpret_cast<const float4*>(&bias[og * 4]);

    const int wid = blockIdx.x * (blockDim.x >> 6) + (threadIdx.x >> 6);
    const int v0 = wid * NODES_PER_WAVE;
    if (v0 >= N_NODES) return;
    const int v1 = (v0 + NODES_PER_WAVE < N_NODES) ? v0 + NODES_PER_WAVE : N_NODES;

    for (int v = v0; v < v1; ++v) {
        const int end = rend[v];
        int e = end - deg[v];

        unsigned acc01 = 0u, acc23 = 0u, acc45 = 0u, acc67 = 0u;
        if (es == 0) {   // self term (eps = 0)
            const uint4 sv = xh[(size_t)v * 4 + fq];
            PK_ADD(sv);
        }

        for (; e + 32 <= end; e += 32) {
            const int r0 = esrc[e + es] & 0x1FFFF;
            const int r1 = esrc[e + 16 + es] & 0x1FFFF;
            const uint4 g0 = xh[(size_t)r0 * 4 + fq];
            const uint4 g1 = xh[(size_t)r1 * 4 + fq];
            PK_ADD(g0); PK_ADD(g1);
        }
        if (e + 16 <= end) {
            const int r0 = esrc[e + es] & 0x1FFFF;
            const uint4 g0 = xh[(size_t)r0 * 4 + fq];
            PK_ADD(g0);
            e += 16;
        }
        const int rem = end - e;
        if (es < rem) {
            const int r0 = esrc[e + es] & 0x1FFFF;
            const uint4 g0 = xh[(size_t)r0 * 4 + fq];
            PK_ADD(g0);
        }

#pragma unroll
        for (int off = 4; off <= 32; off <<= 1) {
            acc01 = hadd2u(acc01, (unsigned)__shfl_xor((int)acc01, off));
            acc23 = hadd2u(acc23, (unsigned)__shfl_xor((int)acc23, off));
            acc45 = hadd2u(acc45, (unsigned)__shfl_xor((int)acc45, off));
            acc67 = hadd2u(acc67, (unsigned)__shfl_xor((int)acc67, off));
        }

        const int s = ig >> 1;
        const int hi = ig & 1;
        const unsigned u0 = (unsigned)__shfl((int)acc01, s);
        const unsigned u1 = (unsigned)__shfl((int)acc23, s);
        const unsigned u2 = (unsigned)__shfl((int)acc45, s);
        const unsigned u3 = (unsigned)__shfl((int)acc67, s);
        const unsigned ua = hi ? u2 : u0;
        const unsigned ub = hi ? u3 : u1;
        const float q0 = lo2f(ua), q1 = hi2f(ua), q2 = lo2f(ub), q3 = hi2f(ub);

        float y0 = q0 * w[0][0] + q1 * w[1][0] + q2 * w[2][0] + q3 * w[3][0];
        float y1 = q0 * w[0][1] + q1 * w[1][1] + q2 * w[2][1] + q3 * w[3][1];
        float y2 = q0 * w[0][2] + q1 * w[1][2] + q2 * w[2][2] + q3 * w[3][2];
        float y3 = q0 * w[0][3] + q1 * w[1][3] + q2 * w[2][3] + q3 * w[3][3];

#pragma unroll
        for (int off = 8; off <= 32; off <<= 1) {
            y0 += __shfl_xor(y0, off); y1 += __shfl_xor(y1, off);
            y2 += __shfl_xor(y2, off); y3 += __shfl_xor(y3, off);
        }
        y0 += bv.x; y1 += bv.y; y2 += bv.z; y3 += bv.w;
        y0 = fmaxf(y0, 0.f); y1 = fmaxf(y1, 0.f); y2 = fmaxf(y2, 0.f); y3 = fmaxf(y3, 0.f);

        if (ig == 0) {
            uint2 o; o.x = pkh2(y0, y1); o.y = pkh2(y2, y3);
            outh[(size_t)v * 8 + og] = o;
        }
    }
}

// ---- Layer 2, src-major: zero random gathers. Per src-window: stage the
// window's 128 h-rows in LDS (coalesced), stream payload (gdst<<7|srcloc),
// LDS-atomic-add h[src] into acc[graph][33] f32 (pad-33 spreads banks by
// graph id). Self-term folded in. Block flushes its acc to a private slice.
__global__ void __launch_bounds__(256)
layer2_win_kernel(const uint2* __restrict__ hh,       // f16 rows, 8 uint2/row
                  const int* __restrict__ ebuf2,
                  const int* __restrict__ gfill2,
                  const int* __restrict__ graph_ids,
                  float* __restrict__ slices) {       // [L2_BLOCKS][128*33]
    __shared__ float acc[N_GRAPHS * 33];
    __shared__ uint2 hl[WIN][8];
    __shared__ int gl[WIN];
    const int tid = threadIdx.x;
    const int fh = tid & 7;            // feat-half: 4 feats (one uint2)

    for (int i = tid; i < N_GRAPHS * 33; i += 256) acc[i] = 0.f;

    for (int w = blockIdx.x; w < NWINS; w += gridDim.x) {
        const int n0 = w * WIN;
        const int nloc = (N_NODES - n0 < WIN) ? (N_NODES - n0) : WIN;
        __syncthreads();   // protect hl/gl from previous iteration's readers
        for (int i = tid; i < nloc * 8; i += 256)
            hl[i >> 3][i & 7] = hh[(size_t)(n0 + (i >> 3)) * 8 + (i & 7)];
        for (int i = tid; i < nloc; i += 256) gl[i] = graph_ids[n0 + i];
        __syncthreads();

        // self term: h_v -> acc[g(v)]
        for (int base = 0; base < nloc; base += 32) {
            const int n = base + (tid >> 3);
            if (n < nloc) {
                const uint2 hv = hl[n][fh];
                float* a = &acc[gl[n] * 33 + fh * 4];
                atomicAdd(a + 0, lo2f(hv.x)); atomicAdd(a + 1, hi2f(hv.x));
                atomicAdd(a + 2, lo2f(hv.y)); atomicAdd(a + 3, hi2f(hv.y));
            }
        }

        // edges: h[src] -> acc[gdst], 32 edges per 256-thread pass, prefetched
        int cnt = gfill2[w]; if (cnt > CAP) cnt = CAP;
        const int base_e = w * CAP;
        int i = tid >> 3;
        int pw = (i < cnt) ? ebuf2[base_e + i] : -1;
        for (; i < cnt; i += 32) {
            const int pw_next = (i + 32 < cnt) ? ebuf2[base_e + i + 32] : -1;
            const int sl = pw & (WIN - 1);
            const int gd = pw >> 7;
            const uint2 hv = hl[sl][fh];
            float* a = &acc[gd * 33 + fh * 4];
            atomicAdd(a + 0, lo2f(hv.x)); atomicAdd(a + 1, hi2f(hv.x));
            atomicAdd(a + 2, lo2f(hv.y)); atomicAdd(a + 3, hi2f(hv.y));
            pw = pw_next;
        }
    }
    __syncthreads();
    float* os = slices + (size_t)blockIdx.x * (N_GRAPHS * 33);
    for (int i = tid; i < N_GRAPHS * 33; i += 256) os[i] = acc[i];
}

// ---- Reduce slices -> pooled, then the 32x32 matvec + cnt*b2 -> out ----
__global__ void __launch_bounds__(256)
reduce_matvec_kernel(const float* __restrict__ slices,
                     const float* __restrict__ W2,
                     const float* __restrict__ b2,
                     const int* __restrict__ cnt,
                     float* __restrict__ out) {
    __shared__ float part[4][64];
    __shared__ float pl[2][32];
    const int tid = threadIdx.x;
    const int bc = tid >> 6;           // 0..3: slice chunk
    const int jl = tid & 63;           // 0..63: 2 graphs x 32 feats
    const int j = blockIdx.x * 64 + jl;
    const int g = j >> 5, f = j & 31;
    float s = 0.f;
    for (int b = bc; b < L2_BLOCKS; b += 4)
        s += slices[(size_t)b * (N_GRAPHS * 33) + g * 33 + f];
    part[bc][jl] = s;
    __syncthreads();
    if (tid < 64) {
        pl[tid >> 5][tid & 31] = part[0][tid] + part[1][tid] + part[2][tid] + part[3][tid];
    }
    __syncthreads();
    if (tid < 64) {
        const int gl = tid >> 5, of = tid & 31;
        const int gg = blockIdx.x * 2 + gl;
        float y = (float)cnt[gg] * b2[of];
#pragma unroll 8
        for (int k = 0; k < 32; ++k)
            y += pl[gl][k] * W2[k * D + of];
        out[gg * D + of] = y;
    }
}

extern "C" void kernel_launch(void* const* d_in, const int* in_sizes, int n_in,
                              void* d_out, int out_size, void* d_ws, size_t ws_size,
                              hipStream_t stream) {
    const float* feats = (const float*)d_in[0];
    const int* src = (const int*)d_in[1];
    const int* dst = (const int*)d_in[2];
    const int* graph_ids = (const int*)d_in[3];
    const float* W1 = (const float*)d_in[4];
    const float* b1 = (const float*)d_in[5];
    const float* W2 = (const float*)d_in[6];
    const float* b2 = (const float*)d_in[7];
    float* out = (float*)d_out;

    int* gfill  = (int*)d_ws;                              // 1024
    int* gfill2 = gfill + 1024;                            // 1024
    int* cnt    = gfill2 + 1024;                           // 256 (128 used)
    int* wbase  = cnt + 256;                               // 1024
    int* ebuf   = wbase + 1024;                            // NWINS*CAP
    int* esrc   = ebuf + (size_t)NWINS * CAP;              // N_EDGES (packed)
    int* rend   = esrc + N_EDGES;                          // N_NODES
    int* deg    = rend + N_NODES;                          // N_NODES
    int* ebuf2  = deg + N_NODES;                           // NWINS*CAP
    unsigned* xh = (unsigned*)(ebuf2 + (size_t)NWINS * CAP);   // N_NODES*16
    unsigned* hh = xh + (size_t)N_NODES * (D / 2);             // N_NODES*16
    float* slices = (float*)(hh + (size_t)N_NODES * (D / 2));  // L2_BLOCKS*128*33

    const int total_waves = (N_NODES + NODES_PER_WAVE - 1) / NODES_PER_WAVE;  // 12500
    const int layer_blocks = (total_waves + 3) / 4;

    // zero gfill + gfill2 + cnt in one memset
    hipMemsetAsync(gfill, 0, (1024 + 1024 + 256) * sizeof(int), stream);

    // ---- CSR build (dst-sorted, graph-tagged) ----
    bin_kernel<<<256, 512, 0, stream>>>(src, dst, gfill, ebuf);
    wscan_kernel<<<1, 1024, 0, stream>>>(gfill, wbase);
    csr_local_kernel<<<NWINS, 256, 0, stream>>>(ebuf, wbase, graph_ids, esrc, rend, deg);

    // ---- aux: per-graph node counts, f16 features ----
    cnt_hist_kernel<<<(N_NODES + 255) / 256, 256, 0, stream>>>(graph_ids, cnt);
    f32_to_f16_kernel<<<(N_NODES * D / 8 + 255) / 256, 256, 0, stream>>>(feats, (uint4*)xh);

    // ---- Layer 1: hh = f16(relu((x + agg(x)) @ W1 + b1)) ----
    gin_layer1_kernel<<<layer_blocks, 256, 0, stream>>>(
        (const uint4*)xh, esrc, rend, deg, W1, b1, (uint2*)hh);

    // ---- Layer 2, src-major (no random gathers) ----
    bin2_kernel<<<256, 512, 0, stream>>>(esrc, gfill2, ebuf2);
    layer2_win_kernel<<<L2_BLOCKS, 256, 0, stream>>>(
        (const uint2*)hh, ebuf2, gfill2, graph_ids, slices);
    reduce_matvec_kernel<<<RED_BLOCKS, 256, 0, stream>>>(slices, W2, b2, cnt, out);
}